// Round 7
// baseline (326.803 us; speedup 1.0000x reference)
//
#include <hip/hip_runtime.h>
#include <hip/hip_bf16.h>

#define NB 2
#define NL 4096
#define ND 512
#define NH 8
#define NDK 64
#define NM (NB * NL)   // 8192
#define QSCALE 0.18033688011112042f  // 0.125 * log2(e)

typedef short bf16x8_t __attribute__((ext_vector_type(8)));
typedef float f32x4_t __attribute__((ext_vector_type(4)));

// fp32 -> bf16 bits, round-to-nearest-even
static __device__ __forceinline__ unsigned short f2bs(float f) {
  union { float f; unsigned u; } c; c.f = f;
  unsigned r = c.u + 0x7fffu + ((c.u >> 16) & 1u);
  return (unsigned short)(r >> 16);
}
static __device__ __forceinline__ float bs2f(unsigned short s) {
  union { unsigned u; float f; } c; c.u = ((unsigned)s) << 16; return c.f;
}
static __device__ __forceinline__ unsigned pk_bf16(float a, float b) {
  union { __hip_bfloat162 h; unsigned u; } c;
  c.h = __float22bfloat162_rn(make_float2(a, b));
  return c.u;
}

// ---------- pre-pass: W[k][n] fp32 -> transposed hi/lo bf16 planes [n][k] ----------
struct WArgs {
  const float* W[4];
  unsigned short* Th[4];
  unsigned short* Tl[4];
};
__global__ __launch_bounds__(256)
void wsplit_kernel(WArgs a)
{
  const int z = blockIdx.z;
  const float* __restrict__ W = a.W[z];
  const int tid = threadIdx.x;
  const int n = blockIdx.x * 64 + (tid & 63);
  const int kb = blockIdx.y * 64 + (tid >> 6) * 16;
  unsigned short h[16], l[16];
#pragma unroll
  for (int u = 0; u < 16; ++u) {
    const float x = W[(size_t)(kb + u) * ND + n];
    h[u] = f2bs(x);
    l[u] = f2bs(x - bs2f(h[u]));
  }
  unsigned wh[8], wl[8];
#pragma unroll
  for (int p = 0; p < 8; ++p) {
    wh[p] = (unsigned)h[2 * p] | ((unsigned)h[2 * p + 1] << 16);
    wl[p] = (unsigned)l[2 * p] | ((unsigned)l[2 * p + 1] << 16);
  }
  unsigned short* th = a.Th[z] + (size_t)n * ND + kb;
  unsigned short* tl = a.Tl[z] + (size_t)n * ND + kb;
  *(uint4*)th = make_uint4(wh[0], wh[1], wh[2], wh[3]);
  *(uint4*)(th + 8) = make_uint4(wh[4], wh[5], wh[6], wh[7]);
  *(uint4*)tl = make_uint4(wl[0], wl[1], wl[2], wl[3]);
  *(uint4*)(tl + 8) = make_uint4(wl[4], wl[5], wl[6], wl[7]);
}

// ---------- split-bf16 MFMA GEMM core, 128x128 tile, BK=32 ----------
template <bool AFP32, bool ASPLIT, bool HEADOUT>
__device__ __forceinline__ void gemm_core(
    const void* __restrict__ Aptr, const unsigned short* __restrict__ Alo,
    const unsigned short* __restrict__ Bh, const unsigned short* __restrict__ Bl,
    const float* __restrict__ bias, unsigned short* __restrict__ outH,
    float* __restrict__ outF, int m0, int n0, float scale)
{
  __shared__ unsigned short AH[128][36];
  __shared__ unsigned short AL[ASPLIT ? 128 : 1][36];
  __shared__ unsigned short BHs[128][36];
  __shared__ unsigned short BLs[128][36];

  const int tid = threadIdx.x;
  const int lane = tid & 63, w = tid >> 6;
  const int m = lane & 15, quad = lane >> 4;

  f32x4_t acc[2][8];
#pragma unroll
  for (int i = 0; i < 2; ++i)
#pragma unroll
    for (int j = 0; j < 8; ++j) acc[i][j] = (f32x4_t){0.f, 0.f, 0.f, 0.f};

  for (int k0 = 0; k0 < ND; k0 += 32) {
    __syncthreads();
    const int r = tid >> 1, hf = (tid & 1) * 16;
    {  // A tile: 128 rows x 32 elems
      if constexpr (AFP32) {
        const float* s = (const float*)Aptr + (size_t)(m0 + r) * ND + k0 + hf;
        const float4 f0 = *(const float4*)s;
        const float4 f1 = *(const float4*)(s + 4);
        const float4 f2 = *(const float4*)(s + 8);
        const float4 f3 = *(const float4*)(s + 12);
        uint4 u0, u1;
        u0.x = pk_bf16(f0.x, f0.y); u0.y = pk_bf16(f0.z, f0.w);
        u0.z = pk_bf16(f1.x, f1.y); u0.w = pk_bf16(f1.z, f1.w);
        u1.x = pk_bf16(f2.x, f2.y); u1.y = pk_bf16(f2.z, f2.w);
        u1.z = pk_bf16(f3.x, f3.y); u1.w = pk_bf16(f3.z, f3.w);
        *(uint4*)&AH[r][hf] = u0;
        *(uint4*)&AH[r][hf + 8] = u1;
      } else {
        const unsigned short* s = (const unsigned short*)Aptr + (size_t)(m0 + r) * ND + k0 + hf;
        *(uint4*)&AH[r][hf] = *(const uint4*)s;
        *(uint4*)&AH[r][hf + 8] = *(const uint4*)(s + 8);
        if constexpr (ASPLIT) {
          const unsigned short* s2 = Alo + (size_t)(m0 + r) * ND + k0 + hf;
          *(uint4*)&AL[r][hf] = *(const uint4*)s2;
          *(uint4*)&AL[r][hf + 8] = *(const uint4*)(s2 + 8);
        }
      }
    }
    {  // B tiles: 128 rows x 32, hi+lo
      const unsigned short* sh = Bh + (size_t)(n0 + r) * ND + k0 + hf;
      const unsigned short* sl = Bl + (size_t)(n0 + r) * ND + k0 + hf;
      *(uint4*)&BHs[r][hf] = *(const uint4*)sh;
      *(uint4*)&BHs[r][hf + 8] = *(const uint4*)(sh + 8);
      *(uint4*)&BLs[r][hf] = *(const uint4*)sl;
      *(uint4*)&BLs[r][hf + 8] = *(const uint4*)(sl + 8);
    }
    __syncthreads();

    bf16x8_t ah[2], al[2];
#pragma unroll
    for (int i = 0; i < 2; ++i) {
      ah[i] = *(const bf16x8_t*)&AH[w * 32 + 16 * i + m][quad * 8];
      if constexpr (ASPLIT) al[i] = *(const bf16x8_t*)&AL[w * 32 + 16 * i + m][quad * 8];
    }
#pragma unroll
    for (int j = 0; j < 8; ++j) {
      const bf16x8_t bhj = *(const bf16x8_t*)&BHs[16 * j + m][quad * 8];
      const bf16x8_t blj = *(const bf16x8_t*)&BLs[16 * j + m][quad * 8];
#pragma unroll
      for (int i = 0; i < 2; ++i) {
        acc[i][j] = __builtin_amdgcn_mfma_f32_16x16x32_bf16(ah[i], bhj, acc[i][j], 0, 0, 0);
        acc[i][j] = __builtin_amdgcn_mfma_f32_16x16x32_bf16(ah[i], blj, acc[i][j], 0, 0, 0);
        if constexpr (ASPLIT)
          acc[i][j] = __builtin_amdgcn_mfma_f32_16x16x32_bf16(al[i], bhj, acc[i][j], 0, 0, 0);
      }
    }
  }

#pragma unroll
  for (int i = 0; i < 2; ++i)
#pragma unroll
    for (int r = 0; r < 4; ++r) {
      const int mg = m0 + w * 32 + 16 * i + quad * 4 + r;
#pragma unroll
      for (int j = 0; j < 8; ++j) {
        const int n = n0 + 16 * j + m;
        const float c = (acc[i][j][r] + bias[n]) * scale;
        if constexpr (HEADOUT) {
          const int b = mg >> 12, l = mg & (NL - 1);
          const int h = n >> 6, d = n & (NDK - 1);
          outH[(((size_t)(b * NH + h)) * NL + l) * NDK + d] = f2bs(c);
        } else {
          outF[(size_t)mg * ND + n] = c;
        }
      }
    }
}

struct ProjArgs {
  const float* A[3];
  const unsigned short* Bh[3];
  const unsigned short* Bl[3];
  const float* bias[3];
  unsigned short* out[3];
  float scale[3];
};
__global__ __launch_bounds__(256, 4)
void gemm_proj_kernel(ProjArgs a)
{
  const int z = blockIdx.z;
  gemm_core<true, false, true>(a.A[z], nullptr, a.Bh[z], a.Bl[z], a.bias[z], a.out[z],
                               nullptr, blockIdx.x * 128, blockIdx.y * 128, a.scale[z]);
}
__global__ __launch_bounds__(256, 4)
void gemm_out_kernel(const unsigned short* __restrict__ Ahi,
                     const unsigned short* __restrict__ Alo,
                     const unsigned short* __restrict__ Bh,
                     const unsigned short* __restrict__ Bl,
                     const float* __restrict__ bias, float* __restrict__ out)
{
  gemm_core<false, true, false>(Ahi, Alo, Bh, Bl, bias, nullptr, out,
                                blockIdx.x * 128, blockIdx.y * 128, 1.0f);
}

// ---------- V transpose: [bh][l][64] -> [bh][64][l] (LDS-tiled) ----------
__global__ __launch_bounds__(256)
void vtrans_kernel(const unsigned short* __restrict__ src, unsigned short* __restrict__ dst)
{
  __shared__ unsigned short T[64][74];
  const int tid = threadIdx.x;
  const int bh = blockIdx.x >> 6;
  const int lt = blockIdx.x & 63;
  const unsigned short* s = src + ((size_t)bh * NL + lt * 64) * NDK;
  const int r = tid >> 2, c = (tid & 3) * 16;
  *(uint4*)&T[r][c] = *(const uint4*)(s + (size_t)r * NDK + c);
  *(uint4*)&T[r][c + 8] = *(const uint4*)(s + (size_t)r * NDK + c + 8);
  __syncthreads();
  const int d = tid >> 2, l0 = (tid & 3) * 16;
  unsigned short e[16];
#pragma unroll
  for (int u = 0; u < 16; ++u) e[u] = T[l0 + u][d];
  uint4 u0, u1;
  u0.x = (unsigned)e[0] | ((unsigned)e[1] << 16);
  u0.y = (unsigned)e[2] | ((unsigned)e[3] << 16);
  u0.z = (unsigned)e[4] | ((unsigned)e[5] << 16);
  u0.w = (unsigned)e[6] | ((unsigned)e[7] << 16);
  u1.x = (unsigned)e[8] | ((unsigned)e[9] << 16);
  u1.y = (unsigned)e[10] | ((unsigned)e[11] << 16);
  u1.z = (unsigned)e[12] | ((unsigned)e[13] << 16);
  u1.w = (unsigned)e[14] | ((unsigned)e[15] << 16);
  unsigned short* dp = dst + (size_t)bh * NDK * NL + (size_t)d * NL + lt * 64 + l0;
  *(uint4*)dp = u0;
  *(uint4*)(dp + 8) = u1;
}

// ---------- MFMA bf16 flash attention, 128-q tiles, 2-way key-split ----------
// Q pre-scaled by 0.125*log2(e) -> p = exp2(s). l-rowsums via ones-B MFMA.
// V arrives pre-transposed [bh][d][l].
__global__ __launch_bounds__(256, 4)
void attn_kernel(const unsigned short* __restrict__ qh, const unsigned short* __restrict__ kh,
                 const unsigned short* __restrict__ vt_g, float* __restrict__ op,
                 float* __restrict__ lp)
{
  __shared__ unsigned short Ks[64][72];  // [key][d]
  __shared__ unsigned short Vt[64][72];  // [d][key]
  __shared__ unsigned Pt[64][67];        // [key][q-pair word]

  const int tid = threadIdx.x;
  const int w = tid >> 6;
  const int lane = tid & 63;
  const int m = lane & 15;
  const int quad = lane >> 4;

  const int bid = blockIdx.x;
  const int half = bid & 1;
  const int qt = (bid >> 1) & 31;
  const int bh = bid >> 6;               // b*NH + h
  const int kt0 = half * 32, kt1 = kt0 + 32;
  const unsigned short* qb = qh + (size_t)bh * NL * NDK;
  const unsigned short* kb = kh + (size_t)bh * NL * NDK;
  const unsigned short* vb = vt_g + (size_t)bh * NDK * NL;  // [d][l]

  bf16x8_t aq[2][2];
#pragma unroll
  for (int mt = 0; mt < 2; ++mt) {
    const unsigned short* qsrc =
        qb + (size_t)(qt * 128 + w * 32 + mt * 16 + m) * NDK + quad * 8;
    aq[mt][0] = *(const bf16x8_t*)(qsrc);
    aq[mt][1] = *(const bf16x8_t*)(qsrc + 32);
  }

  const short ob = (short)0x3F80;
  const bf16x8_t ones = {ob, ob, ob, ob, ob, ob, ob, ob};

  f32x4_t o[2][4];
#pragma unroll
  for (int mt = 0; mt < 2; ++mt)
#pragma unroll
    for (int nt = 0; nt < 4; ++nt) o[mt][nt] = (f32x4_t){0.f, 0.f, 0.f, 0.f};
  f32x4_t ol[2];
  ol[0] = (f32x4_t){0.f, 0.f, 0.f, 0.f};
  ol[1] = (f32x4_t){0.f, 0.f, 0.f, 0.f};

  const int kr = tid >> 2;
  const int kc = (tid & 3) * 16;

  // prefetch first K/V tile
  uint4 pk0, pk1, pv0, pv1;
  {
    const unsigned short* ksrc = kb + (size_t)(kt0 * 64 + kr) * NDK + kc;
    pk0 = *(const uint4*)ksrc;
    pk1 = *(const uint4*)(ksrc + 8);
    const unsigned short* vsrc = vb + (size_t)kr * NL + kt0 * 64 + kc;
    pv0 = *(const uint4*)vsrc;
    pv1 = *(const uint4*)(vsrc + 8);
  }

  for (int kt = kt0; kt < kt1; ++kt) {
    __syncthreads();
    *(uint4*)&Ks[kr][kc] = pk0;
    *(uint4*)&Ks[kr][kc + 8] = pk1;
    *(uint4*)&Vt[kr][kc] = pv0;
    *(uint4*)&Vt[kr][kc + 8] = pv1;
    if (kt + 1 < kt1) {
      const unsigned short* ksrc = kb + (size_t)((kt + 1) * 64 + kr) * NDK + kc;
      pk0 = *(const uint4*)ksrc;
      pk1 = *(const uint4*)(ksrc + 8);
      const unsigned short* vsrc = vb + (size_t)kr * NL + (kt + 1) * 64 + kc;
      pv0 = *(const uint4*)vsrc;
      pv1 = *(const uint4*)(vsrc + 8);
    }
    __syncthreads();

    // S = Q K^T (pre-scaled); p = exp2(s); pair-pack both m-tiles; Pt write
#pragma unroll
    for (int nt = 0; nt < 4; ++nt) {
      const bf16x8_t b0 = *(const bf16x8_t*)&Ks[16 * nt + m][quad * 8];
      const bf16x8_t b1 = *(const bf16x8_t*)&Ks[16 * nt + m][quad * 8 + 32];
      f32x4_t s0 = (f32x4_t){0.f, 0.f, 0.f, 0.f};
      s0 = __builtin_amdgcn_mfma_f32_16x16x32_bf16(aq[0][0], b0, s0, 0, 0, 0);
      s0 = __builtin_amdgcn_mfma_f32_16x16x32_bf16(aq[0][1], b1, s0, 0, 0, 0);
      f32x4_t s1 = (f32x4_t){0.f, 0.f, 0.f, 0.f};
      s1 = __builtin_amdgcn_mfma_f32_16x16x32_bf16(aq[1][0], b0, s1, 0, 0, 0);
      s1 = __builtin_amdgcn_mfma_f32_16x16x32_bf16(aq[1][1], b1, s1, 0, 0, 0);
      unsigned pw[4];
#pragma unroll
      for (int r = 0; r < 4; ++r)
        pw[r] = pk_bf16(exp2f(s0[r]), exp2f(s1[r]));
      *(uint4*)&Pt[16 * nt + m][w * 16 + quad * 4] =
          make_uint4(pw[0], pw[1], pw[2], pw[3]);
    }
    // Pt is wave-private; lgkmcnt dep handles ordering

    // O += P V ; l += P . 1  (ones-B MFMA)
#pragma unroll
    for (int kb2 = 0; kb2 < 2; ++kb2) {
      unsigned pwv[8];
#pragma unroll
      for (int j = 0; j < 8; ++j)
        pwv[j] = Pt[kb2 * 32 + quad * 8 + j][w * 16 + m];
      union { bf16x8_t v; unsigned d[4]; } pa0, pa1;
#pragma unroll
      for (int t = 0; t < 4; ++t) {
        pa0.d[t] = (pwv[2 * t] & 0xffffu) | (pwv[2 * t + 1] << 16);
        pa1.d[t] = (pwv[2 * t] >> 16) | (pwv[2 * t + 1] & 0xffff0000u);
      }
#pragma unroll
      for (int nt = 0; nt < 4; ++nt) {
        const bf16x8_t vb0 = *(const bf16x8_t*)&Vt[16 * nt + m][kb2 * 32 + quad * 8];
        o[0][nt] = __builtin_amdgcn_mfma_f32_16x16x32_bf16(pa0.v, vb0, o[0][nt], 0, 0, 0);
        o[1][nt] = __builtin_amdgcn_mfma_f32_16x16x32_bf16(pa1.v, vb0, o[1][nt], 0, 0, 0);
      }
      ol[0] = __builtin_amdgcn_mfma_f32_16x16x32_bf16(pa0.v, ones, ol[0], 0, 0, 0);
      ol[1] = __builtin_amdgcn_mfma_f32_16x16x32_bf16(pa1.v, ones, ol[1], 0, 0, 0);
    }
  }

  // epilogue: unnormalized o + partial row sums (every lane holds ol)
  const size_t pbase = (size_t)(half * 16 + bh) * NL;
#pragma unroll
  for (int mt = 0; mt < 2; ++mt) {
    const int q0 = qt * 128 + w * 32 + mt * 16 + quad * 4;
    if (m == 0)
      *(float4*)&lp[pbase + q0] =
          make_float4(ol[mt][0], ol[mt][1], ol[mt][2], ol[mt][3]);
#pragma unroll
    for (int r = 0; r < 4; ++r) {
      float* dst = op + (pbase + q0 + r) * NDK;
#pragma unroll
      for (int nt = 0; nt < 4; ++nt) dst[16 * nt + m] = o[mt][nt][r];
    }
  }
}

// ---------- merge: ctx = (o0+o1)/(l0+l1), emit split-bf16 planes ----------
__global__ __launch_bounds__(256)
void merge_kernel(const float* __restrict__ op, const float* __restrict__ lp,
                  unsigned short* __restrict__ ctxh, unsigned short* __restrict__ ctxl)
{
  const size_t t = (size_t)blockIdx.x * 256 + threadIdx.x;
  const int d0 = (int)(t & 7) * 8;
  const size_t row = t >> 3;               // bh*NL + l
  const float l0 = lp[row];
  const float l1 = lp[row + (size_t)16 * NL];
  const float inv = 1.0f / (l0 + l1);
  const float* a = op + row * NDK + d0;
  const float* c = a + (size_t)16 * NL * NDK;
  const float4 a0 = *(const float4*)a, a1 = *(const float4*)(a + 4);
  const float4 c0 = *(const float4*)c, c1 = *(const float4*)(c + 4);
  const float x[8] = {(a0.x + c0.x) * inv, (a0.y + c0.y) * inv,
                      (a0.z + c0.z) * inv, (a0.w + c0.w) * inv,
                      (a1.x + c1.x) * inv, (a1.y + c1.y) * inv,
                      (a1.z + c1.z) * inv, (a1.w + c1.w) * inv};
  unsigned short hs[8], ls[8];
#pragma unroll
  for (int u = 0; u < 8; ++u) {
    hs[u] = f2bs(x[u]);
    ls[u] = f2bs(x[u] - bs2f(hs[u]));
  }
  const int bh = (int)(row >> 12), l = (int)(row & (NL - 1));
  const int b = bh >> 3, h = bh & 7;
  const size_t dst = ((size_t)(b * NL + l)) * ND + h * 64 + d0;
  uint4 uh, ul;
  uh.x = (unsigned)hs[0] | ((unsigned)hs[1] << 16);
  uh.y = (unsigned)hs[2] | ((unsigned)hs[3] << 16);
  uh.z = (unsigned)hs[4] | ((unsigned)hs[5] << 16);
  uh.w = (unsigned)hs[6] | ((unsigned)hs[7] << 16);
  ul.x = (unsigned)ls[0] | ((unsigned)ls[1] << 16);
  ul.y = (unsigned)ls[2] | ((unsigned)ls[3] << 16);
  ul.z = (unsigned)ls[4] | ((unsigned)ls[5] << 16);
  ul.w = (unsigned)ls[6] | ((unsigned)ls[7] << 16);
  *(uint4*)(ctxh + dst) = uh;
  *(uint4*)(ctxl + dst) = ul;
}

extern "C" void kernel_launch(void* const* d_in, const int* in_sizes, int n_in,
                              void* d_out, int out_size, void* d_ws, size_t ws_size,
                              hipStream_t stream)
{
  const float* q  = (const float*)d_in[0];
  const float* k  = (const float*)d_in[1];
  const float* v  = (const float*)d_in[2];
  const float* Wq = (const float*)d_in[3];
  const float* bq = (const float*)d_in[4];
  const float* Wk = (const float*)d_in[5];
  const float* bk = (const float*)d_in[6];
  const float* Wv = (const float*)d_in[7];
  const float* bv = (const float*)d_in[8];
  const float* Wo = (const float*)d_in[9];
  const float* bo = (const float*)d_in[10];

  const size_t PLANE = (size_t)NM * ND;               // 4.19M elems
  unsigned short* wt = (unsigned short*)d_ws;         // 8 x 512KB weight planes (4 MB)
  unsigned short* qhp = wt + 8 * (size_t)ND * ND;     // 8 MB
  unsigned short* khp = qhp + PLANE;                  // 8 MB
  unsigned short* vtp = khp + PLANE;                  // 8 MB (transposed V)
  float* op = (float*)(vtp + PLANE);                  // 33.5 MB fp32 partials
  float* lp = op + 2 * (size_t)16 * NL * NDK;         // 0.5 MB
  unsigned short* vhp_tmp = (unsigned short*)op;      // proj V out; dead before attn writes op
  unsigned short* ctxh = qhp;                         // aliases, dead after attn
  unsigned short* ctxl = khp;

  unsigned short* wth[4], *wtl[4];
  for (int i = 0; i < 4; ++i) {
    wth[i] = wt + (size_t)(2 * i) * ND * ND;
    wtl[i] = wt + (size_t)(2 * i + 1) * ND * ND;
  }

  // 1) transpose+split weight matrices
  WArgs wa;
  wa.W[0] = Wq; wa.W[1] = Wk; wa.W[2] = Wv; wa.W[3] = Wo;
  for (int i = 0; i < 4; ++i) { wa.Th[i] = wth[i]; wa.Tl[i] = wtl[i]; }
  wsplit_kernel<<<dim3(8, 8, 4), 256, 0, stream>>>(wa);

  // 2) three projection GEMMs (Q pre-scaled by 0.125*log2e)
  ProjArgs pa;
  pa.A[0] = q; pa.A[1] = k; pa.A[2] = v;
  pa.Bh[0] = wth[0]; pa.Bl[0] = wtl[0];
  pa.Bh[1] = wth[1]; pa.Bl[1] = wtl[1];
  pa.Bh[2] = wth[2]; pa.Bl[2] = wtl[2];
  pa.bias[0] = bq; pa.bias[1] = bk; pa.bias[2] = bv;
  pa.out[0] = qhp; pa.out[1] = khp; pa.out[2] = vhp_tmp;
  pa.scale[0] = QSCALE; pa.scale[1] = 1.0f; pa.scale[2] = 1.0f;
  gemm_proj_kernel<<<dim3(NM / 128, ND / 128, 3), 256, 0, stream>>>(pa);

  // 3) transpose V head-planes: [bh][l][64] -> [bh][64][l]
  vtrans_kernel<<<dim3(NB * NH * (NL / 64)), 256, 0, stream>>>(vhp_tmp, vtp);

  // 4) attention, 2-way key split (1024 blocks)
  attn_kernel<<<dim3(NB * NH * (NL / 128) * 2), 256, 0, stream>>>(qhp, khp, vtp, op, lp);

  // 5) merge partials -> split-bf16 ctx planes
  merge_kernel<<<dim3((16 * NL * NDK) / (256 * 8)), 256, 0, stream>>>(op, lp, ctxh, ctxl);

  // 6) output GEMM (3-term split, fp32 out)
  gemm_out_kernel<<<dim3(NM / 128, ND / 128), 256, 0, stream>>>(
      ctxh, ctxl, wth[3], wtl[3], bo, (float*)d_out);
}

// Round 8
// 288.713 us; speedup vs baseline: 1.1319x; 1.1319x over previous
//
#include <hip/hip_runtime.h>
#include <hip/hip_bf16.h>

#define NB 2
#define NL 4096
#define ND 512
#define NH 8
#define NDK 64
#define NM (NB * NL)   // 8192
#define QSCALE 0.18033688011112042f  // 0.125 * log2(e)

typedef short bf16x8_t __attribute__((ext_vector_type(8)));
typedef float f32x4_t __attribute__((ext_vector_type(4)));

// fp32 -> bf16 bits, round-to-nearest-even
static __device__ __forceinline__ unsigned short f2bs(float f) {
  union { float f; unsigned u; } c; c.f = f;
  unsigned r = c.u + 0x7fffu + ((c.u >> 16) & 1u);
  return (unsigned short)(r >> 16);
}
static __device__ __forceinline__ float bs2f(unsigned short s) {
  union { unsigned u; float f; } c; c.u = ((unsigned)s) << 16; return c.f;
}
static __device__ __forceinline__ unsigned pk_bf16(float a, float b) {
  union { __hip_bfloat162 h; unsigned u; } c;
  c.h = __float22bfloat162_rn(make_float2(a, b));
  return c.u;
}

// ---------- pre-pass: round q,k,v fp32 -> bf16 planes (one launch, y=3) ----------
__global__ __launch_bounds__(256)
void round3_kernel(const float* __restrict__ s0, const float* __restrict__ s1,
                   const float* __restrict__ s2, unsigned short* __restrict__ d0,
                   unsigned short* __restrict__ d1, unsigned short* __restrict__ d2)
{
  const float* s = blockIdx.y == 0 ? s0 : (blockIdx.y == 1 ? s1 : s2);
  unsigned short* d = blockIdx.y == 0 ? d0 : (blockIdx.y == 1 ? d1 : d2);
  const size_t i = ((size_t)blockIdx.x * 256 + threadIdx.x) * 8;
  const float4 f0 = *(const float4*)(s + i);
  const float4 f1 = *(const float4*)(s + i + 4);
  uint4 o;
  o.x = pk_bf16(f0.x, f0.y);
  o.y = pk_bf16(f0.z, f0.w);
  o.z = pk_bf16(f1.x, f1.y);
  o.w = pk_bf16(f1.z, f1.w);
  *(uint4*)(d + i) = o;
}

// ---------- pre-pass: W[k][n] fp32 -> transposed hi/lo bf16 planes [n][k] ----------
struct WArgs {
  const float* W[4];
  unsigned short* Th[4];
  unsigned short* Tl[4];
};
__global__ __launch_bounds__(256)
void wsplit_kernel(WArgs a)
{
  const int z = blockIdx.z;
  const float* __restrict__ W = a.W[z];
  const int tid = threadIdx.x;
  const int n = blockIdx.x * 64 + (tid & 63);
  const int kb = blockIdx.y * 64 + (tid >> 6) * 16;
  unsigned short h[16], l[16];
#pragma unroll
  for (int u = 0; u < 16; ++u) {
    const float x = W[(size_t)(kb + u) * ND + n];
    h[u] = f2bs(x);
    l[u] = f2bs(x - bs2f(h[u]));
  }
  unsigned wh[8], wl[8];
#pragma unroll
  for (int p = 0; p < 8; ++p) {
    wh[p] = (unsigned)h[2 * p] | ((unsigned)h[2 * p + 1] << 16);
    wl[p] = (unsigned)l[2 * p] | ((unsigned)l[2 * p + 1] << 16);
  }
  unsigned short* th = a.Th[z] + (size_t)n * ND + kb;
  unsigned short* tl = a.Tl[z] + (size_t)n * ND + kb;
  *(uint4*)th = make_uint4(wh[0], wh[1], wh[2], wh[3]);
  *(uint4*)(th + 8) = make_uint4(wh[4], wh[5], wh[6], wh[7]);
  *(uint4*)tl = make_uint4(wl[0], wl[1], wl[2], wl[3]);
  *(uint4*)(tl + 8) = make_uint4(wl[4], wl[5], wl[6], wl[7]);
}

// ---------- split-bf16 MFMA GEMM core, 128x128 tile, BK=32, reg prefetch ----------
// A: bf16 plane(s) [M][512]. B: transposed bf16 planes [n][k].
// ASPLIT: 3-term (Ahi.Bhi + Ahi.Blo + Alo.Bhi); else 2-term.
// HEADOUT: bf16 into [B][H][L][64]; else fp32 flat [M][512].
template <bool ASPLIT, bool HEADOUT>
__device__ __forceinline__ void gemm_core(
    const unsigned short* __restrict__ Ahi, const unsigned short* __restrict__ Alo,
    const unsigned short* __restrict__ Bh, const unsigned short* __restrict__ Bl,
    const float* __restrict__ bias, unsigned short* __restrict__ outH,
    float* __restrict__ outF, int m0, int n0, float scale)
{
  __shared__ unsigned short AH[128][36];
  __shared__ unsigned short AL[ASPLIT ? 128 : 1][36];
  __shared__ unsigned short BHs[128][36];
  __shared__ unsigned short BLs[128][36];

  const int tid = threadIdx.x;
  const int lane = tid & 63, w = tid >> 6;
  const int m = lane & 15, quad = lane >> 4;
  const int r = tid >> 1, hf = (tid & 1) * 16;

  const unsigned short* aRow = Ahi + (size_t)(m0 + r) * ND + hf;
  const unsigned short* alRow = ASPLIT ? (Alo + (size_t)(m0 + r) * ND + hf) : nullptr;
  const unsigned short* bhRow = Bh + (size_t)(n0 + r) * ND + hf;
  const unsigned short* blRow = Bl + (size_t)(n0 + r) * ND + hf;

  // prefetch k0 = 0
  uint4 ra0 = *(const uint4*)(aRow);
  uint4 ra1 = *(const uint4*)(aRow + 8);
  uint4 rl0, rl1;
  if constexpr (ASPLIT) {
    rl0 = *(const uint4*)(alRow);
    rl1 = *(const uint4*)(alRow + 8);
  }
  uint4 rbh0 = *(const uint4*)(bhRow);
  uint4 rbh1 = *(const uint4*)(bhRow + 8);
  uint4 rbl0 = *(const uint4*)(blRow);
  uint4 rbl1 = *(const uint4*)(blRow + 8);

  f32x4_t acc[2][8];
#pragma unroll
  for (int i = 0; i < 2; ++i)
#pragma unroll
    for (int j = 0; j < 8; ++j) acc[i][j] = (f32x4_t){0.f, 0.f, 0.f, 0.f};

  for (int k0 = 0; k0 < ND; k0 += 32) {
    __syncthreads();
    *(uint4*)&AH[r][hf] = ra0;
    *(uint4*)&AH[r][hf + 8] = ra1;
    if constexpr (ASPLIT) {
      *(uint4*)&AL[r][hf] = rl0;
      *(uint4*)&AL[r][hf + 8] = rl1;
    }
    *(uint4*)&BHs[r][hf] = rbh0;
    *(uint4*)&BHs[r][hf + 8] = rbh1;
    *(uint4*)&BLs[r][hf] = rbl0;
    *(uint4*)&BLs[r][hf + 8] = rbl1;
    if (k0 + 32 < ND) {  // prefetch next K-slab (overlaps MFMA below)
      const int kn = k0 + 32;
      ra0 = *(const uint4*)(aRow + kn);
      ra1 = *(const uint4*)(aRow + kn + 8);
      if constexpr (ASPLIT) {
        rl0 = *(const uint4*)(alRow + kn);
        rl1 = *(const uint4*)(alRow + kn + 8);
      }
      rbh0 = *(const uint4*)(bhRow + kn);
      rbh1 = *(const uint4*)(bhRow + kn + 8);
      rbl0 = *(const uint4*)(blRow + kn);
      rbl1 = *(const uint4*)(blRow + kn + 8);
    }
    __syncthreads();

    bf16x8_t ah[2], al[2];
#pragma unroll
    for (int i = 0; i < 2; ++i) {
      ah[i] = *(const bf16x8_t*)&AH[w * 32 + 16 * i + m][quad * 8];
      if constexpr (ASPLIT) al[i] = *(const bf16x8_t*)&AL[w * 32 + 16 * i + m][quad * 8];
    }
#pragma unroll
    for (int j = 0; j < 8; ++j) {
      const bf16x8_t bhj = *(const bf16x8_t*)&BHs[16 * j + m][quad * 8];
      const bf16x8_t blj = *(const bf16x8_t*)&BLs[16 * j + m][quad * 8];
#pragma unroll
      for (int i = 0; i < 2; ++i) {
        acc[i][j] = __builtin_amdgcn_mfma_f32_16x16x32_bf16(ah[i], bhj, acc[i][j], 0, 0, 0);
        acc[i][j] = __builtin_amdgcn_mfma_f32_16x16x32_bf16(ah[i], blj, acc[i][j], 0, 0, 0);
        if constexpr (ASPLIT)
          acc[i][j] = __builtin_amdgcn_mfma_f32_16x16x32_bf16(al[i], bhj, acc[i][j], 0, 0, 0);
      }
    }
  }

#pragma unroll
  for (int i = 0; i < 2; ++i)
#pragma unroll
    for (int rr = 0; rr < 4; ++rr) {
      const int mg = m0 + w * 32 + 16 * i + quad * 4 + rr;
#pragma unroll
      for (int j = 0; j < 8; ++j) {
        const int n = n0 + 16 * j + m;
        const float c = (acc[i][j][rr] + bias[n]) * scale;
        if constexpr (HEADOUT) {
          const int b = mg >> 12, l = mg & (NL - 1);
          const int h = n >> 6, d = n & (NDK - 1);
          outH[(((size_t)(b * NH + h)) * NL + l) * NDK + d] = f2bs(c);
        } else {
          outF[(size_t)mg * ND + n] = c;
        }
      }
    }
}

struct ProjArgs {
  const unsigned short* A[3];
  const unsigned short* Bh[3];
  const unsigned short* Bl[3];
  const float* bias[3];
  unsigned short* out[3];
  float scale[3];
};
__global__ __launch_bounds__(256, 2)
void gemm_proj_kernel(ProjArgs a)
{
  const int z = blockIdx.z;
  gemm_core<false, true>(a.A[z], nullptr, a.Bh[z], a.Bl[z], a.bias[z], a.out[z],
                         nullptr, blockIdx.x * 128, blockIdx.y * 128, a.scale[z]);
}
__global__ __launch_bounds__(256, 2)
void gemm_out_kernel(const unsigned short* __restrict__ Ahi,
                     const unsigned short* __restrict__ Alo,
                     const unsigned short* __restrict__ Bh,
                     const unsigned short* __restrict__ Bl,
                     const float* __restrict__ bias, float* __restrict__ out)
{
  gemm_core<true, false>(Ahi, Alo, Bh, Bl, bias, nullptr, out,
                         blockIdx.x * 128, blockIdx.y * 128, 1.0f);
}

// ---------- V transpose: [bh][l][64] -> [bh][64][l] (LDS-tiled) ----------
__global__ __launch_bounds__(256)
void vtrans_kernel(const unsigned short* __restrict__ src, unsigned short* __restrict__ dst)
{
  __shared__ unsigned short T[64][74];
  const int tid = threadIdx.x;
  const int bh = blockIdx.x >> 6;
  const int lt = blockIdx.x & 63;
  const unsigned short* s = src + ((size_t)bh * NL + lt * 64) * NDK;
  const int r = tid >> 2, c = (tid & 3) * 16;
  *(uint4*)&T[r][c] = *(const uint4*)(s + (size_t)r * NDK + c);
  *(uint4*)&T[r][c + 8] = *(const uint4*)(s + (size_t)r * NDK + c + 8);
  __syncthreads();
  const int d = tid >> 2, l0 = (tid & 3) * 16;
  unsigned short e[16];
#pragma unroll
  for (int u = 0; u < 16; ++u) e[u] = T[l0 + u][d];
  uint4 u0, u1;
  u0.x = (unsigned)e[0] | ((unsigned)e[1] << 16);
  u0.y = (unsigned)e[2] | ((unsigned)e[3] << 16);
  u0.z = (unsigned)e[4] | ((unsigned)e[5] << 16);
  u0.w = (unsigned)e[6] | ((unsigned)e[7] << 16);
  u1.x = (unsigned)e[8] | ((unsigned)e[9] << 16);
  u1.y = (unsigned)e[10] | ((unsigned)e[11] << 16);
  u1.z = (unsigned)e[12] | ((unsigned)e[13] << 16);
  u1.w = (unsigned)e[14] | ((unsigned)e[15] << 16);
  unsigned short* dp = dst + (size_t)bh * NDK * NL + (size_t)d * NL + lt * 64 + l0;
  *(uint4*)dp = u0;
  *(uint4*)(dp + 8) = u1;
}

// ---------- MFMA bf16 flash attention, 128-q tiles, 2-way key-split ----------
// Q pre-scaled by 0.125*log2(e) -> p = exp2(s). l-rowsums via ones-B MFMA.
// V arrives pre-transposed [bh][d][l].
__global__ __launch_bounds__(256, 4)
void attn_kernel(const unsigned short* __restrict__ qh, const unsigned short* __restrict__ kh,
                 const unsigned short* __restrict__ vt_g, float* __restrict__ op,
                 float* __restrict__ lp)
{
  __shared__ unsigned short Ks[64][72];  // [key][d]
  __shared__ unsigned short Vt[64][72];  // [d][key]
  __shared__ unsigned Pt[64][67];        // [key][q-pair word]

  const int tid = threadIdx.x;
  const int w = tid >> 6;
  const int lane = tid & 63;
  const int m = lane & 15;
  const int quad = lane >> 4;

  const int bid = blockIdx.x;
  const int half = bid & 1;
  const int qt = (bid >> 1) & 31;
  const int bh = bid >> 6;               // b*NH + h
  const int kt0 = half * 32, kt1 = kt0 + 32;
  const unsigned short* qb = qh + (size_t)bh * NL * NDK;
  const unsigned short* kb = kh + (size_t)bh * NL * NDK;
  const unsigned short* vb = vt_g + (size_t)bh * NDK * NL;  // [d][l]

  bf16x8_t aq[2][2];
#pragma unroll
  for (int mt = 0; mt < 2; ++mt) {
    const unsigned short* qsrc =
        qb + (size_t)(qt * 128 + w * 32 + mt * 16 + m) * NDK + quad * 8;
    aq[mt][0] = *(const bf16x8_t*)(qsrc);
    aq[mt][1] = *(const bf16x8_t*)(qsrc + 32);
  }

  const short ob = (short)0x3F80;
  const bf16x8_t ones = {ob, ob, ob, ob, ob, ob, ob, ob};

  f32x4_t o[2][4];
#pragma unroll
  for (int mt = 0; mt < 2; ++mt)
#pragma unroll
    for (int nt = 0; nt < 4; ++nt) o[mt][nt] = (f32x4_t){0.f, 0.f, 0.f, 0.f};
  f32x4_t ol[2];
  ol[0] = (f32x4_t){0.f, 0.f, 0.f, 0.f};
  ol[1] = (f32x4_t){0.f, 0.f, 0.f, 0.f};

  const int kr = tid >> 2;
  const int kc = (tid & 3) * 16;

  uint4 pk0, pk1, pv0, pv1;
  {
    const unsigned short* ksrc = kb + (size_t)(kt0 * 64 + kr) * NDK + kc;
    pk0 = *(const uint4*)ksrc;
    pk1 = *(const uint4*)(ksrc + 8);
    const unsigned short* vsrc = vb + (size_t)kr * NL + kt0 * 64 + kc;
    pv0 = *(const uint4*)vsrc;
    pv1 = *(const uint4*)(vsrc + 8);
  }

  for (int kt = kt0; kt < kt1; ++kt) {
    __syncthreads();
    *(uint4*)&Ks[kr][kc] = pk0;
    *(uint4*)&Ks[kr][kc + 8] = pk1;
    *(uint4*)&Vt[kr][kc] = pv0;
    *(uint4*)&Vt[kr][kc + 8] = pv1;
    if (kt + 1 < kt1) {
      const unsigned short* ksrc = kb + (size_t)((kt + 1) * 64 + kr) * NDK + kc;
      pk0 = *(const uint4*)ksrc;
      pk1 = *(const uint4*)(ksrc + 8);
      const unsigned short* vsrc = vb + (size_t)kr * NL + (kt + 1) * 64 + kc;
      pv0 = *(const uint4*)vsrc;
      pv1 = *(const uint4*)(vsrc + 8);
    }
    __syncthreads();

    // S = Q K^T (pre-scaled); p = exp2(s); pair-pack both m-tiles; Pt write
#pragma unroll
    for (int nt = 0; nt < 4; ++nt) {
      const bf16x8_t b0 = *(const bf16x8_t*)&Ks[16 * nt + m][quad * 8];
      const bf16x8_t b1 = *(const bf16x8_t*)&Ks[16 * nt + m][quad * 8 + 32];
      f32x4_t s0 = (f32x4_t){0.f, 0.f, 0.f, 0.f};
      s0 = __builtin_amdgcn_mfma_f32_16x16x32_bf16(aq[0][0], b0, s0, 0, 0, 0);
      s0 = __builtin_amdgcn_mfma_f32_16x16x32_bf16(aq[0][1], b1, s0, 0, 0, 0);
      f32x4_t s1 = (f32x4_t){0.f, 0.f, 0.f, 0.f};
      s1 = __builtin_amdgcn_mfma_f32_16x16x32_bf16(aq[1][0], b0, s1, 0, 0, 0);
      s1 = __builtin_amdgcn_mfma_f32_16x16x32_bf16(aq[1][1], b1, s1, 0, 0, 0);
      unsigned pw[4];
#pragma unroll
      for (int r = 0; r < 4; ++r)
        pw[r] = pk_bf16(exp2f(s0[r]), exp2f(s1[r]));
      *(uint4*)&Pt[16 * nt + m][w * 16 + quad * 4] =
          make_uint4(pw[0], pw[1], pw[2], pw[3]);
    }
    // Pt is wave-private; lgkmcnt dep handles ordering

    // O += P V ; l += P . 1  (ones-B MFMA)
#pragma unroll
    for (int kb2 = 0; kb2 < 2; ++kb2) {
      unsigned pwv[8];
#pragma unroll
      for (int j = 0; j < 8; ++j)
        pwv[j] = Pt[kb2 * 32 + quad * 8 + j][w * 16 + m];
      union { bf16x8_t v; unsigned d[4]; } pa0, pa1;
#pragma unroll
      for (int t = 0; t < 4; ++t) {
        pa0.d[t] = (pwv[2 * t] & 0xffffu) | (pwv[2 * t + 1] << 16);
        pa1.d[t] = (pwv[2 * t] >> 16) | (pwv[2 * t + 1] & 0xffff0000u);
      }
#pragma unroll
      for (int nt = 0; nt < 4; ++nt) {
        const bf16x8_t vb0 = *(const bf16x8_t*)&Vt[16 * nt + m][kb2 * 32 + quad * 8];
        o[0][nt] = __builtin_amdgcn_mfma_f32_16x16x32_bf16(pa0.v, vb0, o[0][nt], 0, 0, 0);
        o[1][nt] = __builtin_amdgcn_mfma_f32_16x16x32_bf16(pa1.v, vb0, o[1][nt], 0, 0, 0);
      }
      ol[0] = __builtin_amdgcn_mfma_f32_16x16x32_bf16(pa0.v, ones, ol[0], 0, 0, 0);
      ol[1] = __builtin_amdgcn_mfma_f32_16x16x32_bf16(pa1.v, ones, ol[1], 0, 0, 0);
    }
  }

  const size_t pbase = (size_t)(half * 16 + bh) * NL;
#pragma unroll
  for (int mt = 0; mt < 2; ++mt) {
    const int q0 = qt * 128 + w * 32 + mt * 16 + quad * 4;
    if (m == 0)
      *(float4*)&lp[pbase + q0] =
          make_float4(ol[mt][0], ol[mt][1], ol[mt][2], ol[mt][3]);
#pragma unroll
    for (int r = 0; r < 4; ++r) {
      float* dst = op + (pbase + q0 + r) * NDK;
#pragma unroll
      for (int nt = 0; nt < 4; ++nt) dst[16 * nt + m] = o[mt][nt][r];
    }
  }
}

// ---------- merge: ctx = (o0+o1)/(l0+l1), emit split-bf16 planes ----------
__global__ __launch_bounds__(256)
void merge_kernel(const float* __restrict__ op, const float* __restrict__ lp,
                  unsigned short* __restrict__ ctxh, unsigned short* __restrict__ ctxl)
{
  const size_t t = (size_t)blockIdx.x * 256 + threadIdx.x;
  const int d0 = (int)(t & 7) * 8;
  const size_t row = t >> 3;               // bh*NL + l
  const float l0 = lp[row];
  const float l1 = lp[row + (size_t)16 * NL];
  const float inv = 1.0f / (l0 + l1);
  const float* a = op + row * NDK + d0;
  const float* c = a + (size_t)16 * NL * NDK;
  const float4 a0 = *(const float4*)a, a1 = *(const float4*)(a + 4);
  const float4 c0 = *(const float4*)c, c1 = *(const float4*)(c + 4);
  const float x[8] = {(a0.x + c0.x) * inv, (a0.y + c0.y) * inv,
                      (a0.z + c0.z) * inv, (a0.w + c0.w) * inv,
                      (a1.x + c1.x) * inv, (a1.y + c1.y) * inv,
                      (a1.z + c1.z) * inv, (a1.w + c1.w) * inv};
  unsigned short hs[8], ls[8];
#pragma unroll
  for (int u = 0; u < 8; ++u) {
    hs[u] = f2bs(x[u]);
    ls[u] = f2bs(x[u] - bs2f(hs[u]));
  }
  const int bh = (int)(row >> 12), l = (int)(row & (NL - 1));
  const int b = bh >> 3, h = bh & 7;
  const size_t dst = ((size_t)(b * NL + l)) * ND + h * 64 + d0;
  uint4 uh, ul;
  uh.x = (unsigned)hs[0] | ((unsigned)hs[1] << 16);
  uh.y = (unsigned)hs[2] | ((unsigned)hs[3] << 16);
  uh.z = (unsigned)hs[4] | ((unsigned)hs[5] << 16);
  uh.w = (unsigned)hs[6] | ((unsigned)hs[7] << 16);
  ul.x = (unsigned)ls[0] | ((unsigned)ls[1] << 16);
  ul.y = (unsigned)ls[2] | ((unsigned)ls[3] << 16);
  ul.z = (unsigned)ls[4] | ((unsigned)ls[5] << 16);
  ul.w = (unsigned)ls[6] | ((unsigned)ls[7] << 16);
  *(uint4*)(ctxh + dst) = uh;
  *(uint4*)(ctxl + dst) = ul;
}

extern "C" void kernel_launch(void* const* d_in, const int* in_sizes, int n_in,
                              void* d_out, int out_size, void* d_ws, size_t ws_size,
                              hipStream_t stream)
{
  const float* q  = (const float*)d_in[0];
  const float* k  = (const float*)d_in[1];
  const float* v  = (const float*)d_in[2];
  const float* Wq = (const float*)d_in[3];
  const float* bq = (const float*)d_in[4];
  const float* Wk = (const float*)d_in[5];
  const float* bk = (const float*)d_in[6];
  const float* Wv = (const float*)d_in[7];
  const float* bv = (const float*)d_in[8];
  const float* Wo = (const float*)d_in[9];
  const float* bo = (const float*)d_in[10];

  const size_t PLANE = (size_t)NM * ND;               // 4.19M elems (8.39 MB bf16)
  unsigned short* wt = (unsigned short*)d_ws;         // 8 x 512KB weight planes (4 MB)
  unsigned short* qhp = wt + 8 * (size_t)ND * ND;     // 8 MB
  unsigned short* khp = qhp + PLANE;                  // 8 MB
  unsigned short* vtp = khp + PLANE;                  // 8 MB (transposed V)
  float* op = (float*)(vtp + PLANE);                  // 33.55 MB fp32 partials
  float* lp = op + 2 * (size_t)16 * NL * NDK;         // 0.5 MB
  // aliases inside op region (all dead before attn writes op):
  unsigned short* qb = (unsigned short*)op;           // round3 out / proj in
  unsigned short* kb = qb + PLANE;
  unsigned short* vb = kb + PLANE;
  unsigned short* vhp_tmp = vb + PLANE;               // proj V out / vtrans in
  unsigned short* ctxh = qhp;                         // merge out (qhp dead after attn)
  unsigned short* ctxl = khp;

  unsigned short* wth[4], *wtl[4];
  for (int i = 0; i < 4; ++i) {
    wth[i] = wt + (size_t)(2 * i) * ND * ND;
    wtl[i] = wt + (size_t)(2 * i + 1) * ND * ND;
  }

  // 1) round q,k,v to bf16 planes
  round3_kernel<<<dim3(PLANE / (256 * 8), 3), 256, 0, stream>>>(q, k, v, qb, kb, vb);

  // 2) transpose+split weight matrices
  WArgs wa;
  wa.W[0] = Wq; wa.W[1] = Wk; wa.W[2] = Wv; wa.W[3] = Wo;
  for (int i = 0; i < 4; ++i) { wa.Th[i] = wth[i]; wa.Tl[i] = wtl[i]; }
  wsplit_kernel<<<dim3(8, 8, 4), 256, 0, stream>>>(wa);

  // 3) three projection GEMMs (bf16 A, 2-term; Q pre-scaled by 0.125*log2e)
  ProjArgs pa;
  pa.A[0] = qb; pa.A[1] = kb; pa.A[2] = vb;
  pa.Bh[0] = wth[0]; pa.Bl[0] = wtl[0];
  pa.Bh[1] = wth[1]; pa.Bl[1] = wtl[1];
  pa.Bh[2] = wth[2]; pa.Bl[2] = wtl[2];
  pa.bias[0] = bq; pa.bias[1] = bk; pa.bias[2] = bv;
  pa.out[0] = qhp; pa.out[1] = khp; pa.out[2] = vhp_tmp;
  pa.scale[0] = QSCALE; pa.scale[1] = 1.0f; pa.scale[2] = 1.0f;
  gemm_proj_kernel<<<dim3(NM / 128, ND / 128, 3), 256, 0, stream>>>(pa);

  // 4) transpose V head-planes: [bh][l][64] -> [bh][64][l]
  vtrans_kernel<<<dim3(NB * NH * (NL / 64)), 256, 0, stream>>>(vhp_tmp, vtp);

  // 5) attention, 2-way key split (1024 blocks)
  attn_kernel<<<dim3(NB * NH * (NL / 128) * 2), 256, 0, stream>>>(qhp, khp, vtp, op, lp);

  // 6) merge partials -> split-bf16 ctx planes
  merge_kernel<<<dim3((16 * NL * NDK) / (256 * 8)), 256, 0, stream>>>(op, lp, ctxh, ctxl);

  // 7) output GEMM (3-term split, fp32 out)
  gemm_out_kernel<<<dim3(NM / 128, ND / 128), 256, 0, stream>>>(
      ctxh, ctxl, wth[3], wtl[3], bo, (float*)d_out);
}

// Round 9
// 285.849 us; speedup vs baseline: 1.1433x; 1.0100x over previous
//
#include <hip/hip_runtime.h>
#include <hip/hip_bf16.h>

#define NB 2
#define NL 4096
#define ND 512
#define NH 8
#define NDK 64
#define NM (NB * NL)   // 8192
#define QSCALE 0.18033688011112042f  // 0.125 * log2(e)

typedef short bf16x8_t __attribute__((ext_vector_type(8)));
typedef float f32x4_t __attribute__((ext_vector_type(4)));

// fp32 -> bf16 bits, round-to-nearest-even
static __device__ __forceinline__ unsigned short f2bs(float f) {
  union { float f; unsigned u; } c; c.f = f;
  unsigned r = c.u + 0x7fffu + ((c.u >> 16) & 1u);
  return (unsigned short)(r >> 16);
}
static __device__ __forceinline__ float bs2f(unsigned short s) {
  union { unsigned u; float f; } c; c.u = ((unsigned)s) << 16; return c.f;
}
static __device__ __forceinline__ unsigned pk_bf16(float a, float b) {
  union { __hip_bfloat162 h; unsigned u; } c;
  c.h = __float22bfloat162_rn(make_float2(a, b));
  return c.u;
}

// ---------- pre-pass: round q,k,v fp32 -> bf16 planes (one launch, y=3) ----------
__global__ __launch_bounds__(256)
void round3_kernel(const float* __restrict__ s0, const float* __restrict__ s1,
                   const float* __restrict__ s2, unsigned short* __restrict__ d0,
                   unsigned short* __restrict__ d1, unsigned short* __restrict__ d2)
{
  const float* s = blockIdx.y == 0 ? s0 : (blockIdx.y == 1 ? s1 : s2);
  unsigned short* d = blockIdx.y == 0 ? d0 : (blockIdx.y == 1 ? d1 : d2);
  const size_t i = ((size_t)blockIdx.x * 256 + threadIdx.x) * 8;
  const float4 f0 = *(const float4*)(s + i);
  const float4 f1 = *(const float4*)(s + i + 4);
  uint4 o;
  o.x = pk_bf16(f0.x, f0.y);
  o.y = pk_bf16(f0.z, f0.w);
  o.z = pk_bf16(f1.x, f1.y);
  o.w = pk_bf16(f1.z, f1.w);
  *(uint4*)(d + i) = o;
}

// ---------- pre-pass: W[k][n] fp32 -> transposed hi/lo bf16 planes [n][k] ----------
struct WArgs {
  const float* W[4];
  unsigned short* Th[4];
  unsigned short* Tl[4];
};
__global__ __launch_bounds__(256)
void wsplit_kernel(WArgs a)
{
  const int z = blockIdx.z;
  const float* __restrict__ W = a.W[z];
  const int tid = threadIdx.x;
  const int n = blockIdx.x * 64 + (tid & 63);
  const int kb = blockIdx.y * 64 + (tid >> 6) * 16;
  unsigned short h[16], l[16];
#pragma unroll
  for (int u = 0; u < 16; ++u) {
    const float x = W[(size_t)(kb + u) * ND + n];
    h[u] = f2bs(x);
    l[u] = f2bs(x - bs2f(h[u]));
  }
  unsigned wh[8], wl[8];
#pragma unroll
  for (int p = 0; p < 8; ++p) {
    wh[p] = (unsigned)h[2 * p] | ((unsigned)h[2 * p + 1] << 16);
    wl[p] = (unsigned)l[2 * p] | ((unsigned)l[2 * p + 1] << 16);
  }
  unsigned short* th = a.Th[z] + (size_t)n * ND + kb;
  unsigned short* tl = a.Tl[z] + (size_t)n * ND + kb;
  *(uint4*)th = make_uint4(wh[0], wh[1], wh[2], wh[3]);
  *(uint4*)(th + 8) = make_uint4(wh[4], wh[5], wh[6], wh[7]);
  *(uint4*)tl = make_uint4(wl[0], wl[1], wl[2], wl[3]);
  *(uint4*)(tl + 8) = make_uint4(wl[4], wl[5], wl[6], wl[7]);
}

// ---------- split-bf16 MFMA GEMM core, 128 x (NJ*16) tile, BK=32, reg prefetch ----------
// A: bf16 plane(s) [M][512]. B: transposed bf16 planes [n][k].
// ASPLIT: 3-term (Ahi.Bhi + Ahi.Blo + Alo.Bhi); else 2-term.
// OUTMODE: 0 = bf16 head layout [B][H][L][64]; 1 = fp32 flat [M][512];
//          2 = bf16 transposed head layout [bh][d][l] (for V).
template <bool ASPLIT, int NJ, int OUTMODE>
__device__ __forceinline__ void gemm_core(
    const unsigned short* __restrict__ Ahi, const unsigned short* __restrict__ Alo,
    const unsigned short* __restrict__ Bh, const unsigned short* __restrict__ Bl,
    const float* __restrict__ bias, unsigned short* __restrict__ outH,
    float* __restrict__ outF, int m0, int n0, float scale)
{
  __shared__ unsigned short AH[128][36];
  __shared__ unsigned short AL[ASPLIT ? 128 : 1][36];
  __shared__ unsigned short BHs[NJ * 16][36];
  __shared__ unsigned short BLs[NJ * 16][36];

  const int tid = threadIdx.x;
  const int lane = tid & 63, w = tid >> 6;
  const int m = lane & 15, quad = lane >> 4;
  const int r = tid >> 1, hf = (tid & 1) * 16;
  const int rb = (NJ == 8) ? (tid >> 1) : (tid >> 2);
  const int cb = (NJ == 8) ? ((tid & 1) * 16) : ((tid & 3) * 8);

  const unsigned short* aRow = Ahi + (size_t)(m0 + r) * ND + hf;
  const unsigned short* alRow = ASPLIT ? (Alo + (size_t)(m0 + r) * ND + hf) : nullptr;
  const unsigned short* bhRow = Bh + (size_t)(n0 + rb) * ND + cb;
  const unsigned short* blRow = Bl + (size_t)(n0 + rb) * ND + cb;

  // prefetch k0 = 0
  uint4 ra0 = *(const uint4*)(aRow);
  uint4 ra1 = *(const uint4*)(aRow + 8);
  uint4 rl0, rl1;
  if constexpr (ASPLIT) {
    rl0 = *(const uint4*)(alRow);
    rl1 = *(const uint4*)(alRow + 8);
  }
  uint4 rbh0 = *(const uint4*)(bhRow);
  uint4 rbl0 = *(const uint4*)(blRow);
  uint4 rbh1, rbl1;
  if constexpr (NJ == 8) {
    rbh1 = *(const uint4*)(bhRow + 8);
    rbl1 = *(const uint4*)(blRow + 8);
  }

  f32x4_t acc[2][NJ];
#pragma unroll
  for (int i = 0; i < 2; ++i)
#pragma unroll
    for (int j = 0; j < NJ; ++j) acc[i][j] = (f32x4_t){0.f, 0.f, 0.f, 0.f};

  for (int k0 = 0; k0 < ND; k0 += 32) {
    __syncthreads();
    *(uint4*)&AH[r][hf] = ra0;
    *(uint4*)&AH[r][hf + 8] = ra1;
    if constexpr (ASPLIT) {
      *(uint4*)&AL[r][hf] = rl0;
      *(uint4*)&AL[r][hf + 8] = rl1;
    }
    *(uint4*)&BHs[rb][cb] = rbh0;
    *(uint4*)&BLs[rb][cb] = rbl0;
    if constexpr (NJ == 8) {
      *(uint4*)&BHs[rb][cb + 8] = rbh1;
      *(uint4*)&BLs[rb][cb + 8] = rbl1;
    }
    if (k0 + 32 < ND) {  // prefetch next K-slab (overlaps MFMA below)
      const int kn = k0 + 32;
      ra0 = *(const uint4*)(aRow + kn);
      ra1 = *(const uint4*)(aRow + kn + 8);
      if constexpr (ASPLIT) {
        rl0 = *(const uint4*)(alRow + kn);
        rl1 = *(const uint4*)(alRow + kn + 8);
      }
      rbh0 = *(const uint4*)(bhRow + kn);
      rbl0 = *(const uint4*)(blRow + kn);
      if constexpr (NJ == 8) {
        rbh1 = *(const uint4*)(bhRow + kn + 8);
        rbl1 = *(const uint4*)(blRow + kn + 8);
      }
    }
    __syncthreads();

    bf16x8_t ah[2], al[2];
#pragma unroll
    for (int i = 0; i < 2; ++i) {
      ah[i] = *(const bf16x8_t*)&AH[w * 32 + 16 * i + m][quad * 8];
      if constexpr (ASPLIT) al[i] = *(const bf16x8_t*)&AL[w * 32 + 16 * i + m][quad * 8];
    }
#pragma unroll
    for (int j = 0; j < NJ; ++j) {
      const bf16x8_t bhj = *(const bf16x8_t*)&BHs[16 * j + m][quad * 8];
      const bf16x8_t blj = *(const bf16x8_t*)&BLs[16 * j + m][quad * 8];
#pragma unroll
      for (int i = 0; i < 2; ++i) {
        acc[i][j] = __builtin_amdgcn_mfma_f32_16x16x32_bf16(ah[i], bhj, acc[i][j], 0, 0, 0);
        acc[i][j] = __builtin_amdgcn_mfma_f32_16x16x32_bf16(ah[i], blj, acc[i][j], 0, 0, 0);
        if constexpr (ASPLIT)
          acc[i][j] = __builtin_amdgcn_mfma_f32_16x16x32_bf16(al[i], bhj, acc[i][j], 0, 0, 0);
      }
    }
  }

  if constexpr (OUTMODE != 2) {
#pragma unroll
    for (int i = 0; i < 2; ++i)
#pragma unroll
      for (int rr = 0; rr < 4; ++rr) {
        const int mg = m0 + w * 32 + 16 * i + quad * 4 + rr;
#pragma unroll
        for (int j = 0; j < NJ; ++j) {
          const int n = n0 + 16 * j + m;
          const float c = (acc[i][j][rr] + bias[n]) * scale;
          if constexpr (OUTMODE == 0) {
            const int b = mg >> 12, l = mg & (NL - 1);
            const int h = n >> 6, d = n & (NDK - 1);
            outH[(((size_t)(b * NH + h)) * NL + l) * NDK + d] = f2bs(c);
          } else {
            outF[(size_t)mg * ND + n] = c;
          }
        }
      }
  } else {
    // VTRANS: bounce through LDS (reuse BHs) in 4 passes of 32 l-rows,
    // store coalesced to [bh][d][l].
    unsigned short* T = &BHs[0][0];   // used as [128 n][34 shorts]
    const int bb = m0 >> 12;
    const int lbase = m0 & (NL - 1);
#pragma unroll 1
    for (int p = 0; p < 4; ++p) {
      __syncthreads();
      if (w == p) {
#pragma unroll
        for (int i = 0; i < 2; ++i)
#pragma unroll
          for (int j = 0; j < NJ; ++j) {
            const int n = 16 * j + m;
            const float bv = bias[n0 + n];
            const unsigned w0 = pk_bf16((acc[i][j][0] + bv) * scale,
                                        (acc[i][j][1] + bv) * scale);
            const unsigned w1 = pk_bf16((acc[i][j][2] + bv) * scale,
                                        (acc[i][j][3] + bv) * scale);
            *(uint2*)&T[n * 34 + 16 * i + quad * 4] = make_uint2(w0, w1);
          }
      }
      __syncthreads();
      const int n = tid >> 1;
      const int l0 = (tid & 1) * 16;
      const uint4 t0 = *(const uint4*)&T[n * 34 + l0];
      const uint4 t1 = *(const uint4*)&T[n * 34 + l0 + 8];
      const int ng = n0 + n;
      const int h = ng >> 6, d = ng & (NDK - 1);
      unsigned short* dp =
          outH + (((size_t)(bb * NH + h)) * NDK + d) * NL + lbase + 32 * p + l0;
      *(uint4*)dp = t0;
      *(uint4*)(dp + 8) = t1;
    }
  }
}

struct ProjArgs {
  const unsigned short* A[3];
  const unsigned short* Bh[3];
  const unsigned short* Bl[3];
  const float* bias[3];
  unsigned short* out[3];
  float scale[3];
};
__global__ __launch_bounds__(256, 3)
void gemm_proj_kernel(ProjArgs a)
{
  const int z = blockIdx.z;
  if (z < 2)
    gemm_core<false, 8, 0>(a.A[z], nullptr, a.Bh[z], a.Bl[z], a.bias[z], a.out[z],
                           nullptr, blockIdx.x * 128, blockIdx.y * 128, a.scale[z]);
  else
    gemm_core<false, 8, 2>(a.A[2], nullptr, a.Bh[2], a.Bl[2], a.bias[2], a.out[2],
                           nullptr, blockIdx.x * 128, blockIdx.y * 128, a.scale[2]);
}
__global__ __launch_bounds__(256, 3)
void gemm_out_kernel(const unsigned short* __restrict__ Ahi,
                     const unsigned short* __restrict__ Alo,
                     const unsigned short* __restrict__ Bh,
                     const unsigned short* __restrict__ Bl,
                     const float* __restrict__ bias, float* __restrict__ out)
{
  gemm_core<true, 4, 1>(Ahi, Alo, Bh, Bl, bias, nullptr, out,
                        blockIdx.x * 128, blockIdx.y * 64, 1.0f);
}

// ---------- MFMA bf16 flash attention, 128-q tiles, 2-way key-split ----------
// Q pre-scaled by 0.125*log2(e) -> p = exp2(s). l-rowsums via ones-B MFMA.
// V arrives pre-transposed [bh][d][l].
__global__ __launch_bounds__(256, 4)
void attn_kernel(const unsigned short* __restrict__ qh, const unsigned short* __restrict__ kh,
                 const unsigned short* __restrict__ vt_g, float* __restrict__ op,
                 float* __restrict__ lp)
{
  __shared__ unsigned short Ks[64][72];  // [key][d]
  __shared__ unsigned short Vt[64][72];  // [d][key]
  __shared__ unsigned Pt[64][67];        // [key][q-pair word]

  const int tid = threadIdx.x;
  const int w = tid >> 6;
  const int lane = tid & 63;
  const int m = lane & 15;
  const int quad = lane >> 4;

  const int bid = blockIdx.x;
  const int half = bid & 1;
  const int qt = (bid >> 1) & 31;
  const int bh = bid >> 6;               // b*NH + h
  const int kt0 = half * 32, kt1 = kt0 + 32;
  const unsigned short* qb = qh + (size_t)bh * NL * NDK;
  const unsigned short* kb = kh + (size_t)bh * NL * NDK;
  const unsigned short* vb = vt_g + (size_t)bh * NDK * NL;  // [d][l]

  bf16x8_t aq[2][2];
#pragma unroll
  for (int mt = 0; mt < 2; ++mt) {
    const unsigned short* qsrc =
        qb + (size_t)(qt * 128 + w * 32 + mt * 16 + m) * NDK + quad * 8;
    aq[mt][0] = *(const bf16x8_t*)(qsrc);
    aq[mt][1] = *(const bf16x8_t*)(qsrc + 32);
  }

  const short ob = (short)0x3F80;
  const bf16x8_t ones = {ob, ob, ob, ob, ob, ob, ob, ob};

  f32x4_t o[2][4];
#pragma unroll
  for (int mt = 0; mt < 2; ++mt)
#pragma unroll
    for (int nt = 0; nt < 4; ++nt) o[mt][nt] = (f32x4_t){0.f, 0.f, 0.f, 0.f};
  f32x4_t ol[2];
  ol[0] = (f32x4_t){0.f, 0.f, 0.f, 0.f};
  ol[1] = (f32x4_t){0.f, 0.f, 0.f, 0.f};

  const int kr = tid >> 2;
  const int kc = (tid & 3) * 16;

  uint4 pk0, pk1, pv0, pv1;
  {
    const unsigned short* ksrc = kb + (size_t)(kt0 * 64 + kr) * NDK + kc;
    pk0 = *(const uint4*)ksrc;
    pk1 = *(const uint4*)(ksrc + 8);
    const unsigned short* vsrc = vb + (size_t)kr * NL + kt0 * 64 + kc;
    pv0 = *(const uint4*)vsrc;
    pv1 = *(const uint4*)(vsrc + 8);
  }

  for (int kt = kt0; kt < kt1; ++kt) {
    __syncthreads();
    *(uint4*)&Ks[kr][kc] = pk0;
    *(uint4*)&Ks[kr][kc + 8] = pk1;
    *(uint4*)&Vt[kr][kc] = pv0;
    *(uint4*)&Vt[kr][kc + 8] = pv1;
    if (kt + 1 < kt1) {
      const unsigned short* ksrc = kb + (size_t)((kt + 1) * 64 + kr) * NDK + kc;
      pk0 = *(const uint4*)ksrc;
      pk1 = *(const uint4*)(ksrc + 8);
      const unsigned short* vsrc = vb + (size_t)kr * NL + (kt + 1) * 64 + kc;
      pv0 = *(const uint4*)vsrc;
      pv1 = *(const uint4*)(vsrc + 8);
    }
    __syncthreads();

    // S = Q K^T (pre-scaled); p = exp2(s); pair-pack both m-tiles; Pt write
#pragma unroll
    for (int nt = 0; nt < 4; ++nt) {
      const bf16x8_t b0 = *(const bf16x8_t*)&Ks[16 * nt + m][quad * 8];
      const bf16x8_t b1 = *(const bf16x8_t*)&Ks[16 * nt + m][quad * 8 + 32];
      f32x4_t s0 = (f32x4_t){0.f, 0.f, 0.f, 0.f};
      s0 = __builtin_amdgcn_mfma_f32_16x16x32_bf16(aq[0][0], b0, s0, 0, 0, 0);
      s0 = __builtin_amdgcn_mfma_f32_16x16x32_bf16(aq[0][1], b1, s0, 0, 0, 0);
      f32x4_t s1 = (f32x4_t){0.f, 0.f, 0.f, 0.f};
      s1 = __builtin_amdgcn_mfma_f32_16x16x32_bf16(aq[1][0], b0, s1, 0, 0, 0);
      s1 = __builtin_amdgcn_mfma_f32_16x16x32_bf16(aq[1][1], b1, s1, 0, 0, 0);
      unsigned pw[4];
#pragma unroll
      for (int r = 0; r < 4; ++r)
        pw[r] = pk_bf16(exp2f(s0[r]), exp2f(s1[r]));
      *(uint4*)&Pt[16 * nt + m][w * 16 + quad * 4] =
          make_uint4(pw[0], pw[1], pw[2], pw[3]);
    }
    // Pt is wave-private; lgkmcnt dep handles ordering

    // O += P V ; l += P . 1  (ones-B MFMA)
#pragma unroll
    for (int kb2 = 0; kb2 < 2; ++kb2) {
      unsigned pwv[8];
#pragma unroll
      for (int j = 0; j < 8; ++j)
        pwv[j] = Pt[kb2 * 32 + quad * 8 + j][w * 16 + m];
      union { bf16x8_t v; unsigned d[4]; } pa0, pa1;
#pragma unroll
      for (int t = 0; t < 4; ++t) {
        pa0.d[t] = (pwv[2 * t] & 0xffffu) | (pwv[2 * t + 1] << 16);
        pa1.d[t] = (pwv[2 * t] >> 16) | (pwv[2 * t + 1] & 0xffff0000u);
      }
#pragma unroll
      for (int nt = 0; nt < 4; ++nt) {
        const bf16x8_t vb0 = *(const bf16x8_t*)&Vt[16 * nt + m][kb2 * 32 + quad * 8];
        o[0][nt] = __builtin_amdgcn_mfma_f32_16x16x32_bf16(pa0.v, vb0, o[0][nt], 0, 0, 0);
        o[1][nt] = __builtin_amdgcn_mfma_f32_16x16x32_bf16(pa1.v, vb0, o[1][nt], 0, 0, 0);
      }
      ol[0] = __builtin_amdgcn_mfma_f32_16x16x32_bf16(pa0.v, ones, ol[0], 0, 0, 0);
      ol[1] = __builtin_amdgcn_mfma_f32_16x16x32_bf16(pa1.v, ones, ol[1], 0, 0, 0);
    }
  }

  const size_t pbase = (size_t)(half * 16 + bh) * NL;
#pragma unroll
  for (int mt = 0; mt < 2; ++mt) {
    const int q0 = qt * 128 + w * 32 + mt * 16 + quad * 4;
    if (m == 0)
      *(float4*)&lp[pbase + q0] =
          make_float4(ol[mt][0], ol[mt][1], ol[mt][2], ol[mt][3]);
#pragma unroll
    for (int r = 0; r < 4; ++r) {
      float* dst = op + (pbase + q0 + r) * NDK;
#pragma unroll
      for (int nt = 0; nt < 4; ++nt) dst[16 * nt + m] = o[mt][nt][r];
    }
  }
}

// ---------- merge: ctx = (o0+o1)/(l0+l1), emit split-bf16 planes ----------
__global__ __launch_bounds__(256)
void merge_kernel(const float* __restrict__ op, const float* __restrict__ lp,
                  unsigned short* __restrict__ ctxh, unsigned short* __restrict__ ctxl)
{
  const size_t t = (size_t)blockIdx.x * 256 + threadIdx.x;
  const int d0 = (int)(t & 7) * 8;
  const size_t row = t >> 3;               // bh*NL + l
  const float l0 = lp[row];
  const float l1 = lp[row + (size_t)16 * NL];
  const float inv = 1.0f / (l0 + l1);
  const float* a = op + row * NDK + d0;
  const float* c = a + (size_t)16 * NL * NDK;
  const float4 a0 = *(const float4*)a, a1 = *(const float4*)(a + 4);
  const float4 c0 = *(const float4*)c, c1 = *(const float4*)(c + 4);
  const float x[8] = {(a0.x + c0.x) * inv, (a0.y + c0.y) * inv,
                      (a0.z + c0.z) * inv, (a0.w + c0.w) * inv,
                      (a1.x + c1.x) * inv, (a1.y + c1.y) * inv,
                      (a1.z + c1.z) * inv, (a1.w + c1.w) * inv};
  unsigned short hs[8], ls[8];
#pragma unroll
  for (int u = 0; u < 8; ++u) {
    hs[u] = f2bs(x[u]);
    ls[u] = f2bs(x[u] - bs2f(hs[u]));
  }
  const int bh = (int)(row >> 12), l = (int)(row & (NL - 1));
  const int b = bh >> 3, h = bh & 7;
  const size_t dst = ((size_t)(b * NL + l)) * ND + h * 64 + d0;
  uint4 uh, ul;
  uh.x = (unsigned)hs[0] | ((unsigned)hs[1] << 16);
  uh.y = (unsigned)hs[2] | ((unsigned)hs[3] << 16);
  uh.z = (unsigned)hs[4] | ((unsigned)hs[5] << 16);
  uh.w = (unsigned)hs[6] | ((unsigned)hs[7] << 16);
  ul.x = (unsigned)ls[0] | ((unsigned)ls[1] << 16);
  ul.y = (unsigned)ls[2] | ((unsigned)ls[3] << 16);
  ul.z = (unsigned)ls[4] | ((unsigned)ls[5] << 16);
  ul.w = (unsigned)ls[6] | ((unsigned)ls[7] << 16);
  *(uint4*)(ctxh + dst) = uh;
  *(uint4*)(ctxl + dst) = ul;
}

extern "C" void kernel_launch(void* const* d_in, const int* in_sizes, int n_in,
                              void* d_out, int out_size, void* d_ws, size_t ws_size,
                              hipStream_t stream)
{
  const float* q  = (const float*)d_in[0];
  const float* k  = (const float*)d_in[1];
  const float* v  = (const float*)d_in[2];
  const float* Wq = (const float*)d_in[3];
  const float* bq = (const float*)d_in[4];
  const float* Wk = (const float*)d_in[5];
  const float* bk = (const float*)d_in[6];
  const float* Wv = (const float*)d_in[7];
  const float* bv = (const float*)d_in[8];
  const float* Wo = (const float*)d_in[9];
  const float* bo = (const float*)d_in[10];

  const size_t PLANE = (size_t)NM * ND;               // 4.19M elems (8.39 MB bf16)
  unsigned short* wt = (unsigned short*)d_ws;         // 8 x 512KB weight planes (4 MB)
  unsigned short* qhp = wt + 8 * (size_t)ND * ND;     // 8 MB
  unsigned short* khp = qhp + PLANE;                  // 8 MB
  unsigned short* vtp = khp + PLANE;                  // 8 MB (transposed V, written by proj)
  float* op = (float*)(vtp + PLANE);                  // 33.55 MB fp32 partials
  float* lp = op + 2 * (size_t)16 * NL * NDK;         // 0.5 MB
  // aliases inside op region (all dead before attn writes op):
  unsigned short* qb = (unsigned short*)op;           // round3 out / proj in
  unsigned short* kb = qb + PLANE;
  unsigned short* vb = kb + PLANE;
  unsigned short* ctxh = qhp;                         // merge out (qhp dead after attn)
  unsigned short* ctxl = khp;

  unsigned short* wth[4], *wtl[4];
  for (int i = 0; i < 4; ++i) {
    wth[i] = wt + (size_t)(2 * i) * ND * ND;
    wtl[i] = wt + (size_t)(2 * i + 1) * ND * ND;
  }

  // 1) round q,k,v to bf16 planes
  round3_kernel<<<dim3(PLANE / (256 * 8), 3), 256, 0, stream>>>(q, k, v, qb, kb, vb);

  // 2) transpose+split weight matrices
  WArgs wa;
  wa.W[0] = Wq; wa.W[1] = Wk; wa.W[2] = Wv; wa.W[3] = Wo;
  for (int i = 0; i < 4; ++i) { wa.Th[i] = wth[i]; wa.Tl[i] = wtl[i]; }
  wsplit_kernel<<<dim3(8, 8, 4), 256, 0, stream>>>(wa);

  // 3) three projection GEMMs; V writes transposed head layout directly
  ProjArgs pa;
  pa.A[0] = qb; pa.A[1] = kb; pa.A[2] = vb;
  pa.Bh[0] = wth[0]; pa.Bl[0] = wtl[0];
  pa.Bh[1] = wth[1]; pa.Bl[1] = wtl[1];
  pa.Bh[2] = wth[2]; pa.Bl[2] = wtl[2];
  pa.bias[0] = bq; pa.bias[1] = bk; pa.bias[2] = bv;
  pa.out[0] = qhp; pa.out[1] = khp; pa.out[2] = vtp;
  pa.scale[0] = QSCALE; pa.scale[1] = 1.0f; pa.scale[2] = 1.0f;
  gemm_proj_kernel<<<dim3(NM / 128, ND / 128, 3), 256, 0, stream>>>(pa);

  // 4) attention, 2-way key split (1024 blocks)
  attn_kernel<<<dim3(NB * NH * (NL / 128) * 2), 256, 0, stream>>>(qhp, khp, vtp, op, lp);

  // 5) merge partials -> split-bf16 ctx planes
  merge_kernel<<<dim3((16 * NL * NDK) / (256 * 8)), 256, 0, stream>>>(op, lp, ctxh, ctxl);

  // 6) output GEMM (3-term split, 128x64 tiles, fp32 out)
  gemm_out_kernel<<<dim3(NM / 128, ND / 64), 256, 0, stream>>>(
      ctxh, ctxl, wth[3], wtl[3], bo, (float*)d_out);
}